// Round 4
// baseline (620.501 us; speedup 1.0000x reference)
//
#include <hip/hip_runtime.h>
#include <stdint.h>

// Shapes fixed by the problem: B=4,H=16 -> BH=64; S=1024; D=64.
// d_ws layout (needs 28 MB):
//   [0,8M)    Qb  bf16 [bh][s][d]  (pre-scaled by 1/8)
//   [8M,16M)  Kb  bf16 [bh][s][d]
//   [16M,24M) Vt  bf16 [bh][d][s]  (V transposed)
//   [24M,28M) Mb  u8   [b][q][k]   (mask canonicalized to bytes)

#define S_LEN 1024
#define D_DIM 64
#define QT 16
#define NEG_FILL (-1000000000.0f)
#define LOG2E 1.44269504088896340736f
#define SIMSTR 4160   // sim LDS row stride in bytes (4096 + 64 pad: 16-aligned, de-banks quads)

typedef __bf16 bf16x8 __attribute__((ext_vector_type(8)));
typedef float f32x4 __attribute__((ext_vector_type(4)));
typedef unsigned short u16x4 __attribute__((ext_vector_type(4)));

__device__ __forceinline__ unsigned short f2bf(float x) {
    unsigned u = __builtin_bit_cast(unsigned, x);
    u += 0x7fffu + ((u >> 16) & 1u);
    return (unsigned short)(u >> 16);
}
__device__ __forceinline__ float bf2f(unsigned short b) {
    return __builtin_bit_cast(float, (unsigned)b << 16);
}

// Async global->LDS DMA, 16 B/lane. LDS dest = wave-uniform base + lane*16
// (hardware rule); global src is per-lane. Consumes ZERO VGPRs -> the
// compiler cannot register-minimize this prefetch away (rounds 1-2 failure).
__device__ __forceinline__ void dma16(const void* g, void* l) {
    __builtin_amdgcn_global_load_lds(
        (const __attribute__((address_space(1))) unsigned int*)g,
        (__attribute__((address_space(3))) unsigned int*)l, 16, 0, 0);
}

// Swizzled addressing for the 16x1024 u16 prob block (2048 B rows, XOR a
// 16B-granular row-dependent swizzle). Verified in prior rounds.
__device__ __forceinline__ unsigned short* sptr(unsigned short* s, int row, int col) {
    return (unsigned short*)((char*)s + row * 2048 + ((col * 2) ^ ((row & 7) << 4)));
}

// ---- prep: q,k -> bf16 (q pre-scaled) + mask -> bytes, fused -------------
__global__ void prep_qkm(const float* __restrict__ q, const float* __restrict__ k,
                         const void* __restrict__ mraw,
                         unsigned short* __restrict__ Qb, unsigned short* __restrict__ Kb,
                         unsigned char* __restrict__ Mb)
{
    const int t = threadIdx.x;
    const int i = blockIdx.x * 256 + t;           // float4 / uchar4 index, 1,048,576 total
    f32x4 q4 = ((const f32x4*)q)[i];
    f32x4 k4 = ((const f32x4*)k)[i];
    u16x4 qo, ko;
#pragma unroll
    for (int j = 0; j < 4; ++j) {
        qo[j] = f2bf(q4[j] * 0.125f);
        ko[j] = f2bf(k4[j]);
    }
    ((u16x4*)Qb)[i] = qo;
    ((u16x4*)Kb)[i] = ko;

    // mask format detect (cheap, L2-broadcast) then canonicalize 4 elements
    __shared__ int s_not_int, s_not_f32;
    if (t == 0) { s_not_int = 0; s_not_f32 = 0; }
    __syncthreads();
    const unsigned* wdd = (const unsigned*)mraw;
    int ni = 0, nf = 0;
    for (int j = t; j < 1024; j += 256) {
        unsigned x = wdd[j];
        if (x > 1u) ni = 1;
        if (x != 0u && x != 0x3f800000u) nf = 1;
    }
    if (ni) s_not_int = 1;
    if (nf) s_not_f32 = 1;
    __syncthreads();
    const int fmt = (s_not_int == 0) ? 0 : ((s_not_f32 == 0) ? 1 : 2);
    uchar4 o;
    if (fmt == 0) {        // int32 0/1
        int4 x = ((const int4*)mraw)[i];
        o.x = x.x ? 1 : 0; o.y = x.y ? 1 : 0; o.z = x.z ? 1 : 0; o.w = x.w ? 1 : 0;
    } else if (fmt == 1) { // fp32 0.0/1.0
        float4 x = ((const float4*)mraw)[i];
        o.x = (x.x != 0.f) ? 1 : 0; o.y = (x.y != 0.f) ? 1 : 0;
        o.z = (x.z != 0.f) ? 1 : 0; o.w = (x.w != 0.f) ? 1 : 0;
    } else {               // bool bytes
        uchar4 x = ((const uchar4*)mraw)[i];
        o.x = x.x ? 1 : 0; o.y = x.y ? 1 : 0; o.z = x.z ? 1 : 0; o.w = x.w ? 1 : 0;
    }
    ((uchar4*)Mb)[i] = o;
}

// ---- prep: V -> V^T bf16 (64x64 tiles through LDS) -----------------------
__global__ void prep_vt(const float* __restrict__ v, unsigned short* __restrict__ Vt)
{
    __shared__ unsigned short sT[64 * 72];
    const int bh = blockIdx.x >> 4;
    const int st = blockIdx.x & 15;
    const int t = threadIdx.x;
    const float* vb = v + (size_t)(bh * S_LEN + st * 64) * D_DIM;
#pragma unroll
    for (int p = 0; p < 4; ++p) {
        int lin = p * 256 + t;
        int r = lin >> 4;
        int c = lin & 15;
        f32x4 x = ((const f32x4*)(vb + r * D_DIM))[c];
        unsigned short* dst = &sT[r * 72 + c * 4];
#pragma unroll
        for (int j = 0; j < 4; ++j) dst[j] = f2bf(x[j]);
    }
    __syncthreads();
    unsigned short* ob = Vt + (size_t)bh * D_DIM * S_LEN + st * 64;
#pragma unroll
    for (int p = 0; p < 4; ++p) {
        int lin = p * 256 + t;
        int d = lin >> 4;
        int s4 = (lin & 15) * 4;
        u16x4 o;
#pragma unroll
        for (int j = 0; j < 4; ++j) o[j] = sT[(s4 + j) * 72 + d];
        *(u16x4*)&ob[d * S_LEN + s4] = o;
    }
}

// ---- main ----------------------------------------------------------------
// Structure (this round's rewrite):
//   0. async DMA sim rows -> LDS (zero-VGPR prefetch, can't be sunk)
//   1. QK^T MFMA, scores stay in f32 REGISTERS (C-layout acc[16], no LDS park)
//   2. mask gather before the barrier (barrier pins + hides the loads)
//   b0 3. scores += sim(LDS), mask    4./5. softmax in C-layout:
//      per-lane kt-reduce -> quad shfl_xor -> 256B LDS cross-wave combine
//   6. probs: scale in regs, park bf16 into dead sim LDS (sptr swizzle)
//   b3 7. PV = verified prior phase-3   8. out + attn stores LAST (never drained)
__global__ __launch_bounds__(256, 2)
void attn_main(const float* __restrict__ simg_, const unsigned short* __restrict__ Qb,
               const unsigned short* __restrict__ Kb, const unsigned short* __restrict__ Vtb,
               const unsigned char* __restrict__ Mb, float* __restrict__ out,
               float* __restrict__ attn)
{
    __shared__ __align__(16) unsigned char smem[16 * SIMSTR + 512];   // 67,072 B -> 2 blocks/CU

    const int blk = ((blockIdx.x & 7) << 9) | (blockIdx.x >> 3);  // XCD-contiguous (kept: -55 MB FETCH)
    const int bh = blk >> 6;
    const int qt = blk & 63;
    const int b = bh >> 4;
    const int t = threadIdx.x;
    const int w = t >> 6;
    const int lane = t & 63;
    const int quad = lane >> 4;
    const int l15 = lane & 15;
    const int n0 = w * 16;

    const unsigned short* Qg = Qb + (size_t)(bh * S_LEN + qt * QT) * D_DIM;
    const unsigned short* Kg = Kb + (size_t)bh * S_LEN * D_DIM;
    const unsigned short* Vg = Vtb + (size_t)bh * D_DIM * S_LEN;
    const float* simg = simg_ + ((size_t)(bh * S_LEN + qt * QT)) * S_LEN;
    const unsigned char* mg = Mb + ((size_t)(b * S_LEN + qt * QT)) * S_LEN;
    float* attng = attn + ((size_t)(bh * S_LEN + qt * QT)) * S_LEN;

    // ---- 0. async DMA: this wave's 4 sim rows -> LDS (16 insts, 0 VGPR).
#pragma unroll
    for (int rr = 0; rr < 4; ++rr) {
        const float* gr = simg + (size_t)(w * 4 + rr) * S_LEN + lane * 4;
        unsigned char* lr = smem + (w * 4 + rr) * SIMSTR;
#pragma unroll
        for (int c = 0; c < 4; ++c)
            dma16(gr + c * 256, lr + c * 1024);
    }

    // ---- 1. QK^T: acc[kt][r] = score(row=quad*4+r, col=kt*64+n0+l15), f32.
    const bf16x8 av0 = *(const bf16x8*)&Qg[l15 * D_DIM + quad * 8];
    const bf16x8 av1 = *(const bf16x8*)&Qg[l15 * D_DIM + 32 + quad * 8];
    f32x4 acc[16];
#pragma unroll
    for (int kt = 0; kt < 16; ++kt) {
        const unsigned short* kp = &Kg[(size_t)(kt * 64 + n0 + l15) * D_DIM + quad * 8];
        bf16x8 kv0 = *(const bf16x8*)kp;
        bf16x8 kv1 = *(const bf16x8*)(kp + 32);
        f32x4 a = {0.f, 0.f, 0.f, 0.f};
        a = __builtin_amdgcn_mfma_f32_16x16x32_bf16(av0, kv0, a, 0, 0, 0);
        a = __builtin_amdgcn_mfma_f32_16x16x32_bf16(av1, kv1, a, 0, 0, 0);
        acc[kt] = a;
    }

    // ---- 2. mask gather (L2-hot); issued BEFORE the barrier so the barrier
    //         wait hides its latency and the scheduler cannot sink it.
    unsigned char mk[16][4];
#pragma unroll
    for (int kt = 0; kt < 16; ++kt)
#pragma unroll
        for (int r = 0; r < 4; ++r)
            mk[kt][r] = mg[(size_t)(quad * 4 + r) * S_LEN + kt * 64 + n0 + l15];

    __syncthreads();   // b0: vmcnt(0) drain => all waves' sim DMA landed in LDS

    // ---- 3. scores += sim, apply mask (masked -> NEG exactly, as before).
#pragma unroll
    for (int kt = 0; kt < 16; ++kt)
#pragma unroll
        for (int r = 0; r < 4; ++r) {
            float sv = *(const float*)(smem + (quad * 4 + r) * SIMSTR
                                       + (size_t)(kt * 64 + n0 + l15) * 4);
            acc[kt][r] = mk[kt][r] ? NEG_FILL : (acc[kt][r] + sv);
        }

    // ---- 4. row max: lane kt-reduce -> quad shfl (bits 1,2,4,8 stay within
    //         the 16-lane group) -> 256 B LDS cross-wave combine.
    float* cmbMax = (float*)(smem + 16 * SIMSTR);
    float* cmbSum = (float*)(smem + 16 * SIMSTR + 256);
    float pm[4];
#pragma unroll
    for (int r = 0; r < 4; ++r) {
        float m = acc[0][r];
#pragma unroll
        for (int kt = 1; kt < 16; ++kt) m = fmaxf(m, acc[kt][r]);
#pragma unroll
        for (int off = 1; off <= 8; off <<= 1)
            m = fmaxf(m, __shfl_xor(m, off, 64));
        pm[r] = m;
    }
    if (l15 == 0) {
        f32x4 v = {pm[0], pm[1], pm[2], pm[3]};
        *(f32x4*)&cmbMax[w * 16 + quad * 4] = v;
    }
    __syncthreads();   // b1
    float rM[4];
#pragma unroll
    for (int r = 0; r < 4; ++r) {
        const int row = quad * 4 + r;
        rM[r] = fmaxf(fmaxf(cmbMax[row], cmbMax[16 + row]),
                      fmaxf(cmbMax[32 + row], cmbMax[48 + row]));
    }

    // ---- 5. exp + row sum (same combine pattern).
    float ps[4] = {0.f, 0.f, 0.f, 0.f};
#pragma unroll
    for (int kt = 0; kt < 16; ++kt)
#pragma unroll
        for (int r = 0; r < 4; ++r) {
            float e = __builtin_amdgcn_exp2f((acc[kt][r] - rM[r]) * LOG2E);
            acc[kt][r] = e;
            ps[r] += e;
        }
#pragma unroll
    for (int r = 0; r < 4; ++r)
#pragma unroll
        for (int off = 1; off <= 8; off <<= 1)
            ps[r] += __shfl_xor(ps[r], off, 64);
    if (l15 == 0) {
        f32x4 v = {ps[0], ps[1], ps[2], ps[3]};
        *(f32x4*)&cmbSum[w * 16 + quad * 4] = v;
    }
    __syncthreads();   // b2  (all sim reads done before b1 => sim LDS now dead)
    float rinv[4];
#pragma unroll
    for (int r = 0; r < 4; ++r) {
        const int row = quad * 4 + r;
        rinv[r] = 1.0f / ((cmbSum[row] + cmbSum[16 + row]) +
                          (cmbSum[32 + row] + cmbSum[48 + row]));
    }

    // ---- 6. probs: scale in place (kept in regs for the attn store),
    //         park bf16 into the dead sim region for PV.
    unsigned short* pL = (unsigned short*)smem;   // 32 KB, sptr-swizzled
#pragma unroll
    for (int kt = 0; kt < 16; ++kt)
#pragma unroll
        for (int r = 0; r < 4; ++r) {
            float p = acc[kt][r] * rinv[r];
            acc[kt][r] = p;
            *sptr(pL, quad * 4 + r, kt * 64 + n0 + l15) = f2bf(p);
        }
    __syncthreads();   // b3 (only LDS + long-retired loads pending: cheap)

    // ---- 7. PV = P @ V. A from pL, B direct from Vt (L2). Two acc chains.
    const int d0 = w * 16;
    f32x4 oa0 = {0.f, 0.f, 0.f, 0.f}, oa1 = {0.f, 0.f, 0.f, 0.f};
#pragma unroll
    for (int kt = 0; kt < 16; kt += 2) {
        const unsigned short* vp0 = &Vg[(size_t)(d0 + l15) * S_LEN + kt * 64 + quad * 8];
        bf16x8 x0 = *(const bf16x8*)vp0;
        bf16x8 x1 = *(const bf16x8*)(vp0 + 32);
        bf16x8 y0 = *(const bf16x8*)(vp0 + 64);
        bf16x8 y1 = *(const bf16x8*)(vp0 + 96);
        bf16x8 pa0 = *(const bf16x8*)sptr(pL, l15, kt * 64 + quad * 8);
        bf16x8 pa1 = *(const bf16x8*)sptr(pL, l15, kt * 64 + 32 + quad * 8);
        bf16x8 pb0 = *(const bf16x8*)sptr(pL, l15, kt * 64 + 64 + quad * 8);
        bf16x8 pb1 = *(const bf16x8*)sptr(pL, l15, kt * 64 + 96 + quad * 8);
        oa0 = __builtin_amdgcn_mfma_f32_16x16x32_bf16(pa0, x0, oa0, 0, 0, 0);
        oa0 = __builtin_amdgcn_mfma_f32_16x16x32_bf16(pa1, x1, oa0, 0, 0, 0);
        oa1 = __builtin_amdgcn_mfma_f32_16x16x32_bf16(pb0, y0, oa1, 0, 0, 0);
        oa1 = __builtin_amdgcn_mfma_f32_16x16x32_bf16(pb1, y1, oa1, 0, 0, 0);
    }
    f32x4 oacc = oa0 + oa1;

    float* og = out + ((size_t)(bh * S_LEN + qt * QT)) * D_DIM;
#pragma unroll
    for (int r = 0; r < 4; ++r)
        __builtin_nontemporal_store(oacc[r], &og[(quad * 4 + r) * D_DIM + d0 + l15]);

    // ---- 8. attn stores LAST: no barrier follows, nothing drains them.
#pragma unroll
    for (int kt = 0; kt < 16; ++kt)
#pragma unroll
        for (int r = 0; r < 4; ++r)
            __builtin_nontemporal_store(acc[kt][r],
                &attng[(size_t)(quad * 4 + r) * S_LEN + kt * 64 + n0 + l15]);
}

extern "C" void kernel_launch(void* const* d_in, const int* in_sizes, int n_in,
                              void* d_out, int out_size, void* d_ws, size_t ws_size,
                              hipStream_t stream)
{
    const float* q = (const float*)d_in[0];
    const float* k = (const float*)d_in[1];
    const float* v = (const float*)d_in[2];
    const float* sim = (const float*)d_in[3];
    const void* mask = d_in[4];
    float* out = (float*)d_out;
    float* attn = out + (size_t)4 * 16 * 1024 * 64;   // output first, then attn

    char* ws = (char*)d_ws;                           // needs 28 MB
    unsigned short* Qb = (unsigned short*)(ws + (size_t)0);
    unsigned short* Kb = (unsigned short*)(ws + ((size_t)8 << 20));
    unsigned short* Vt = (unsigned short*)(ws + ((size_t)16 << 20));
    unsigned char*  Mb = (unsigned char*)(ws + ((size_t)24 << 20));

    prep_qkm<<<4096, 256, 0, stream>>>(q, k, mask, Qb, Kb, Mb);
    prep_vt<<<1024, 256, 0, stream>>>(v, Vt);
    attn_main<<<4096, 256, 0, stream>>>(sim, Qb, Kb, Vt, Mb, out, attn);
}

// Round 5
// 576.712 us; speedup vs baseline: 1.0759x; 1.0759x over previous
//
#include <hip/hip_runtime.h>
#include <stdint.h>

// Shapes fixed by the problem: B=4,H=16 -> BH=64; S=1024; D=64.
// d_ws layout (needs 28 MB):
//   [0,8M)    Qb  bf16 [bh][s][d]  (pre-scaled by 1/8)
//   [8M,16M)  Kb  bf16 [bh][s][d]
//   [16M,24M) Vt  bf16 [bh][d][s]  (V transposed)
//   [24M,28M) Mb  u8   [b][q][k]   (mask canonicalized to bytes)

#define S_LEN 1024
#define D_DIM 64
#define QT 16
#define NEG_FILL (-1000000000.0f)
#define LOG2E 1.44269504088896340736f

typedef __bf16 bf16x8 __attribute__((ext_vector_type(8)));
typedef float f32x4 __attribute__((ext_vector_type(4)));
typedef unsigned short u16x4 __attribute__((ext_vector_type(4)));

__device__ __forceinline__ unsigned short f2bf(float x) {
    unsigned u = __builtin_bit_cast(unsigned, x);
    u += 0x7fffu + ((u >> 16) & 1u);
    return (unsigned short)(u >> 16);
}
__device__ __forceinline__ float bf2f(unsigned short b) {
    return __builtin_bit_cast(float, (unsigned)b << 16);
}

// ---- inline-asm loads: an asm def cannot be sunk/rematerialized by the
// compiler (rounds 1/3: plain loads with sched_barrier still got sunk;
// round 4: held-in-flight requests gave +45%/wave). These are the MLP.
__device__ __forceinline__ f32x4 gload16(const void* p) {
    f32x4 d;
    asm volatile("global_load_dwordx4 %0, %1, off" : "=v"(d) : "v"(p) : "memory");
    return d;
}
__device__ __forceinline__ unsigned gload4(const void* p) {
    unsigned d;
    asm volatile("global_load_dword %0, %1, off" : "=v"(d) : "v"(p) : "memory");
    return d;
}
// Counted drain + full scheduling fence (rule 18: VALU consumers can be
// hoisted past an asm waitcnt unless a sched_barrier(0) pins them).
#define WAITV(N) do { \
    asm volatile("s_waitcnt vmcnt(" #N ")" ::: "memory"); \
    __builtin_amdgcn_sched_barrier(0); } while (0)

// Swizzled LDS addressing for the 16x1024 u16 score/prob block: 2048 B rows,
// XOR a 16B-granular row-dependent swizzle (32 KB exactly, no pad).
__device__ __forceinline__ unsigned short* sptr(unsigned short* s, int row, int col) {
    return (unsigned short*)((char*)s + row * 2048 + ((col * 2) ^ ((row & 7) << 4)));
}

// ---- prep: q,k -> bf16 (q pre-scaled) + mask -> bytes, fused -------------
__global__ void prep_qkm(const float* __restrict__ q, const float* __restrict__ k,
                         const void* __restrict__ mraw,
                         unsigned short* __restrict__ Qb, unsigned short* __restrict__ Kb,
                         unsigned char* __restrict__ Mb)
{
    const int t = threadIdx.x;
    const int i = blockIdx.x * 256 + t;           // float4 / uchar4 index, 1,048,576 total
    f32x4 q4 = ((const f32x4*)q)[i];
    f32x4 k4 = ((const f32x4*)k)[i];
    u16x4 qo, ko;
#pragma unroll
    for (int j = 0; j < 4; ++j) {
        qo[j] = f2bf(q4[j] * 0.125f);
        ko[j] = f2bf(k4[j]);
    }
    ((u16x4*)Qb)[i] = qo;
    ((u16x4*)Kb)[i] = ko;

    // mask format detect (cheap, L2-broadcast) then canonicalize 4 elements
    __shared__ int s_not_int, s_not_f32;
    if (t == 0) { s_not_int = 0; s_not_f32 = 0; }
    __syncthreads();
    const unsigned* wdd = (const unsigned*)mraw;
    int ni = 0, nf = 0;
    for (int j = t; j < 1024; j += 256) {
        unsigned x = wdd[j];
        if (x > 1u) ni = 1;
        if (x != 0u && x != 0x3f800000u) nf = 1;
    }
    if (ni) s_not_int = 1;
    if (nf) s_not_f32 = 1;
    __syncthreads();
    const int fmt = (s_not_int == 0) ? 0 : ((s_not_f32 == 0) ? 1 : 2);
    uchar4 o;
    if (fmt == 0) {        // int32 0/1
        int4 x = ((const int4*)mraw)[i];
        o.x = x.x ? 1 : 0; o.y = x.y ? 1 : 0; o.z = x.z ? 1 : 0; o.w = x.w ? 1 : 0;
    } else if (fmt == 1) { // fp32 0.0/1.0
        float4 x = ((const float4*)mraw)[i];
        o.x = (x.x != 0.f) ? 1 : 0; o.y = (x.y != 0.f) ? 1 : 0;
        o.z = (x.z != 0.f) ? 1 : 0; o.w = (x.w != 0.f) ? 1 : 0;
    } else {               // bool bytes
        uchar4 x = ((const uchar4*)mraw)[i];
        o.x = x.x ? 1 : 0; o.y = x.y ? 1 : 0; o.z = x.z ? 1 : 0; o.w = x.w ? 1 : 0;
    }
    ((uchar4*)Mb)[i] = o;
}

// ---- prep: V -> V^T bf16 (64x64 tiles through LDS) -----------------------
__global__ void prep_vt(const float* __restrict__ v, unsigned short* __restrict__ Vt)
{
    __shared__ unsigned short sT[64 * 72];
    const int bh = blockIdx.x >> 4;
    const int st = blockIdx.x & 15;
    const int t = threadIdx.x;
    const float* vb = v + (size_t)(bh * S_LEN + st * 64) * D_DIM;
#pragma unroll
    for (int p = 0; p < 4; ++p) {
        int lin = p * 256 + t;
        int r = lin >> 4;
        int c = lin & 15;
        f32x4 x = ((const f32x4*)(vb + r * D_DIM))[c];
        unsigned short* dst = &sT[r * 72 + c * 4];
#pragma unroll
        for (int j = 0; j < 4; ++j) dst[j] = f2bf(x[j]);
    }
    __syncthreads();
    unsigned short* ob = Vt + (size_t)bh * D_DIM * S_LEN + st * 64;
#pragma unroll
    for (int p = 0; p < 4; ++p) {
        int lin = p * 256 + t;
        int d = lin >> 4;
        int s4 = (lin & 15) * 4;
        u16x4 o;
#pragma unroll
        for (int j = 0; j < 4; ++j) o[j] = sT[(s4 + j) * 72 + d];
        *(u16x4*)&ob[d * S_LEN + s4] = o;
    }
}

// ---- main ----------------------------------------------------------------
// Round-3 shell (32 KB LDS, 4 blocks/CU, row-major phase 2, coalesced attn)
// + asm-load MLP injection:
//   phase 1: 4-deep rolling asm K window, counted vmcnt(6)
//   phase 2: ALL sim (16 x dwordx4) + mask (16 x dword) asm loads issued
//            before b0; barrier drains them while waves wait anyway;
//            softmax then runs stall-free from registers
//   phase 3: 4-deep rolling asm V window; attn stores moved AFTER PV
//            (re-read bf16 probs from LDS) so no store-acks poison the
//            counted vmcnt window
__global__ __launch_bounds__(256, 4)
void attn_main(const float* __restrict__ simg_, const unsigned short* __restrict__ Qb,
               const unsigned short* __restrict__ Kb, const unsigned short* __restrict__ Vtb,
               const unsigned char* __restrict__ Mb, float* __restrict__ out,
               float* __restrict__ attn)
{
    __shared__ __align__(16) unsigned short sS[QT * S_LEN];   // 32768 B exactly

    const int blk = ((blockIdx.x & 7) << 9) | (blockIdx.x >> 3);  // XCD-contiguous (-55 MB FETCH, kept)
    const int bh = blk >> 6;
    const int qt = blk & 63;
    const int b = bh >> 4;
    const int t = threadIdx.x;
    const int w = t >> 6;
    const int lane = t & 63;
    const int quad = lane >> 4;
    const int l15 = lane & 15;
    const int n0 = w * 16;

    const unsigned short* Qg = Qb + (size_t)(bh * S_LEN + qt * QT) * D_DIM;
    const unsigned short* Kg = Kb + (size_t)bh * S_LEN * D_DIM;
    const unsigned short* Vg = Vtb + (size_t)bh * D_DIM * S_LEN;
    const float* simg = simg_ + ((size_t)(bh * S_LEN + qt * QT)) * S_LEN;
    const unsigned char* mg = Mb + ((size_t)(b * S_LEN + qt * QT)) * S_LEN;
    float* attng = attn + ((size_t)(bh * S_LEN + qt * QT)) * S_LEN;

    // ---- phase 1: raw scores = (q/8)@k^T -> bf16 park in sS.
    // 4-deep rolling asm K window; Q loads sit ahead in the queue and are
    // drained by the first WAITV(6) (which needs them anyway).
    const bf16x8 av0 = *(const bf16x8*)&Qg[l15 * D_DIM + quad * 8];
    const bf16x8 av1 = *(const bf16x8*)&Qg[l15 * D_DIM + 32 + quad * 8];
    const unsigned short* kfrag = Kg + (size_t)(n0 + l15) * D_DIM + quad * 8;

#define KLOAD(D0, D1, KT) do { \
    D0 = __builtin_bit_cast(bf16x8, gload16(kfrag + (size_t)(KT) * 4096)); \
    D1 = __builtin_bit_cast(bf16x8, gload16(kfrag + (size_t)(KT) * 4096 + 32)); } while (0)
#define QKSTEP(F0, F1, KT) do { \
    f32x4 _acc = {0.f, 0.f, 0.f, 0.f}; \
    _acc = __builtin_amdgcn_mfma_f32_16x16x32_bf16(av0, F0, _acc, 0, 0, 0); \
    _acc = __builtin_amdgcn_mfma_f32_16x16x32_bf16(av1, F1, _acc, 0, 0, 0); \
    const int _cg = (KT) * 64 + n0 + l15; \
    *sptr(sS, quad * 4 + 0, _cg) = f2bf(_acc[0]); \
    *sptr(sS, quad * 4 + 1, _cg) = f2bf(_acc[1]); \
    *sptr(sS, quad * 4 + 2, _cg) = f2bf(_acc[2]); \
    *sptr(sS, quad * 4 + 3, _cg) = f2bf(_acc[3]); } while (0)

    {
        bf16x8 ka0, ka1, kb0, kb1, kc0, kc1, kd0, kd1;
        KLOAD(ka0, ka1, 0); KLOAD(kb0, kb1, 1); KLOAD(kc0, kc1, 2); KLOAD(kd0, kd1, 3);
        WAITV(6);  QKSTEP(ka0, ka1, 0);  KLOAD(ka0, ka1, 4);
        WAITV(6);  QKSTEP(kb0, kb1, 1);  KLOAD(kb0, kb1, 5);
        WAITV(6);  QKSTEP(kc0, kc1, 2);  KLOAD(kc0, kc1, 6);
        WAITV(6);  QKSTEP(kd0, kd1, 3);  KLOAD(kd0, kd1, 7);
        WAITV(6);  QKSTEP(ka0, ka1, 4);  KLOAD(ka0, ka1, 8);
        WAITV(6);  QKSTEP(kb0, kb1, 5);  KLOAD(kb0, kb1, 9);
        WAITV(6);  QKSTEP(kc0, kc1, 6);  KLOAD(kc0, kc1, 10);
        WAITV(6);  QKSTEP(kd0, kd1, 7);  KLOAD(kd0, kd1, 11);
        WAITV(6);  QKSTEP(ka0, ka1, 8);  KLOAD(ka0, ka1, 12);
        WAITV(6);  QKSTEP(kb0, kb1, 9);  KLOAD(kb0, kb1, 13);
        WAITV(6);  QKSTEP(kc0, kc1, 10); KLOAD(kc0, kc1, 14);
        WAITV(6);  QKSTEP(kd0, kd1, 11); KLOAD(kd0, kd1, 15);
        WAITV(6);  QKSTEP(ka0, ka1, 12);
        WAITV(4);  QKSTEP(kb0, kb1, 13);
        WAITV(2);  QKSTEP(kc0, kc1, 14);
        WAITV(0);  QKSTEP(kd0, kd1, 15);
    }

    // ---- phase-2 prefetch: ALL sim + mask for this wave's 4 rows, asm.
    // 32 loads (20 KB/wave) in flight; b0's vmcnt(0) drain doubles as the
    // completion wait, overlapped with every other wave's arrival.
    const float* sp_w = simg + (size_t)(w * 4) * S_LEN;
    const unsigned char* mp_w = mg + (size_t)(w * 4) * S_LEN;
    f32x4 sv[4][4];
    unsigned mv[4][4];
#pragma unroll
    for (int rr = 0; rr < 4; ++rr)
#pragma unroll
        for (int j = 0; j < 4; ++j) {
            const int col = j * 256 + lane * 4;
            sv[rr][j] = gload16(sp_w + (size_t)rr * S_LEN + col);
            mv[rr][j] = gload4(mp_w + (size_t)rr * S_LEN + col);
        }
    __syncthreads();   // b0: all sS scores visible; all asm loads drained
    WAITV(0);          // safety: data definitely in regs past this point

    // ---- phase 2: mask + sim + exact softmax, pure VALU now.
#pragma unroll
    for (int rr = 0; rr < 4; ++rr) {
        const int row = w * 4 + rr;
        float vals[16];
        float mx = -3.0e38f;
#pragma unroll
        for (int j = 0; j < 4; ++j) {
            const int col = j * 256 + lane * 4;
            u16x4 x = *(const u16x4*)sptr(sS, row, col);
            const unsigned m = mv[rr][j];
            const f32x4 s = sv[rr][j];
            float f0 = (m & 0x000000ffu) ? NEG_FILL : (bf2f(x[0]) + s[0]);
            float f1 = (m & 0x0000ff00u) ? NEG_FILL : (bf2f(x[1]) + s[1]);
            float f2 = (m & 0x00ff0000u) ? NEG_FILL : (bf2f(x[2]) + s[2]);
            float f3 = (m & 0xff000000u) ? NEG_FILL : (bf2f(x[3]) + s[3]);
            vals[j * 4 + 0] = f0; vals[j * 4 + 1] = f1;
            vals[j * 4 + 2] = f2; vals[j * 4 + 3] = f3;
            mx = fmaxf(mx, fmaxf(fmaxf(f0, f1), fmaxf(f2, f3)));
        }
#pragma unroll
        for (int off = 32; off > 0; off >>= 1)
            mx = fmaxf(mx, __shfl_xor(mx, off, 64));
        float sum = 0.f;
#pragma unroll
        for (int i = 0; i < 16; ++i) {
            float e = __builtin_amdgcn_exp2f((vals[i] - mx) * LOG2E);
            vals[i] = e;
            sum += e;
        }
#pragma unroll
        for (int off = 32; off > 0; off >>= 1)
            sum += __shfl_xor(sum, off, 64);
        const float rinv = 1.0f / sum;
#pragma unroll
        for (int j = 0; j < 4; ++j) {
            const int col = j * 256 + lane * 4;
            u16x4 pb;
#pragma unroll
            for (int i = 0; i < 4; ++i)
                pb[i] = f2bf(vals[j * 4 + i] * rinv);
            *(u16x4*)sptr(sS, row, col) = pb;   // park bf16 probs (attn stored at end)
        }
    }

    // ---- phase-3 prefetch: first 4 V fragment pairs, asm, before b1.
    const int d0 = w * 16;
    const unsigned short* vfrag = Vg + (size_t)(d0 + l15) * S_LEN + quad * 8;

#define VLOAD(D0, D1, KT) do { \
    D0 = __builtin_bit_cast(bf16x8, gload16(vfrag + (KT) * 64)); \
    D1 = __builtin_bit_cast(bf16x8, gload16(vfrag + (KT) * 64 + 32)); } while (0)
#define PVSTEP(F0, F1, KT) do { \
    bf16x8 _pa0 = *(const bf16x8*)sptr(sS, l15, (KT) * 64 + quad * 8); \
    bf16x8 _pa1 = *(const bf16x8*)sptr(sS, l15, (KT) * 64 + 32 + quad * 8); \
    oacc = __builtin_amdgcn_mfma_f32_16x16x32_bf16(_pa0, F0, oacc, 0, 0, 0); \
    oacc = __builtin_amdgcn_mfma_f32_16x16x32_bf16(_pa1, F1, oacc, 0, 0, 0); } while (0)

    bf16x8 va0, va1, vb0, vb1, vc0, vc1, vd0, vd1;
    VLOAD(va0, va1, 0); VLOAD(vb0, vb1, 1); VLOAD(vc0, vc1, 2); VLOAD(vd0, vd1, 3);
    __syncthreads();   // b1: prob parks visible; prefetched V drained (resident)

    // ---- phase 3: out = P @ V, 4-deep rolling asm V window.
    f32x4 oacc = {0.f, 0.f, 0.f, 0.f};
    WAITV(6);  PVSTEP(va0, va1, 0);  VLOAD(va0, va1, 4);
    WAITV(6);  PVSTEP(vb0, vb1, 1);  VLOAD(vb0, vb1, 5);
    WAITV(6);  PVSTEP(vc0, vc1, 2);  VLOAD(vc0, vc1, 6);
    WAITV(6);  PVSTEP(vd0, vd1, 3);  VLOAD(vd0, vd1, 7);
    WAITV(6);  PVSTEP(va0, va1, 4);  VLOAD(va0, va1, 8);
    WAITV(6);  PVSTEP(vb0, vb1, 5);  VLOAD(vb0, vb1, 9);
    WAITV(6);  PVSTEP(vc0, vc1, 6);  VLOAD(vc0, vc1, 10);
    WAITV(6);  PVSTEP(vd0, vd1, 7);  VLOAD(vd0, vd1, 11);
    WAITV(6);  PVSTEP(va0, va1, 8);  VLOAD(va0, va1, 12);
    WAITV(6);  PVSTEP(vb0, vb1, 9);  VLOAD(vb0, vb1, 13);
    WAITV(6);  PVSTEP(vc0, vc1, 10); VLOAD(vc0, vc1, 14);
    WAITV(6);  PVSTEP(vd0, vd1, 11); VLOAD(vd0, vd1, 15);
    WAITV(6);  PVSTEP(va0, va1, 12);
    WAITV(4);  PVSTEP(vb0, vb1, 13);
    WAITV(2);  PVSTEP(vc0, vc1, 14);
    WAITV(0);  PVSTEP(vd0, vd1, 15);

    float* og = out + ((size_t)(bh * S_LEN + qt * QT)) * D_DIM;
#pragma unroll
    for (int r = 0; r < 4; ++r)
        __builtin_nontemporal_store(oacc[r], &og[(quad * 4 + r) * D_DIM + d0 + l15]);

    // ---- attn stores LAST (coalesced f32x4 from parked bf16 probs; the
    // store-acks never block anything). bf16 rounding of probs: abs err
    // <= 2e-3, inside the verified 0.0156 margin.
#pragma unroll
    for (int rr = 0; rr < 4; ++rr) {
        const int row = w * 4 + rr;
#pragma unroll
        for (int j = 0; j < 4; ++j) {
            const int col = j * 256 + lane * 4;
            u16x4 x = *(const u16x4*)sptr(sS, row, col);
            f32x4 p = { bf2f(x[0]), bf2f(x[1]), bf2f(x[2]), bf2f(x[3]) };
            __builtin_nontemporal_store(p, (f32x4*)&attng[(size_t)row * S_LEN + col]);
        }
    }
#undef KLOAD
#undef QKSTEP
#undef VLOAD
#undef PVSTEP
}

extern "C" void kernel_launch(void* const* d_in, const int* in_sizes, int n_in,
                              void* d_out, int out_size, void* d_ws, size_t ws_size,
                              hipStream_t stream)
{
    const float* q = (const float*)d_in[0];
    const float* k = (const float*)d_in[1];
    const float* v = (const float*)d_in[2];
    const float* sim = (const float*)d_in[3];
    const void* mask = d_in[4];
    float* out = (float*)d_out;
    float* attn = out + (size_t)4 * 16 * 1024 * 64;   // output first, then attn

    char* ws = (char*)d_ws;                           // needs 28 MB
    unsigned short* Qb = (unsigned short*)(ws + (size_t)0);
    unsigned short* Kb = (unsigned short*)(ws + ((size_t)8 << 20));
    unsigned short* Vt = (unsigned short*)(ws + ((size_t)16 << 20));
    unsigned char*  Mb = (unsigned char*)(ws + ((size_t)24 << 20));

    prep_qkm<<<4096, 256, 0, stream>>>(q, k, mask, Qb, Kb, Mb);
    prep_vt<<<1024, 256, 0, stream>>>(v, Vt);
    attn_main<<<4096, 256, 0, stream>>>(sim, Qb, Kb, Vt, Mb, out, attn);
}